// Round 10
// baseline (271.807 us; speedup 1.0000x reference)
//
#include <hip/hip_runtime.h>
#include <stdint.h>

typedef unsigned short u16;
typedef unsigned long long u64;
typedef __bf16 bf16x8 __attribute__((ext_vector_type(8)));
typedef __bf16 bf16x4 __attribute__((ext_vector_type(4)));
typedef float f32x4 __attribute__((ext_vector_type(4)));
typedef u16 u16x8 __attribute__((ext_vector_type(8)));

// f32 -> bf16 round-to-nearest-even (branchless; inputs finite)
__device__ __forceinline__ u16 f2bf(float x) {
    union { float f; uint32_t u; } c; c.f = x;
    uint32_t r = (c.u + 0x7fffu + ((c.u >> 16) & 1u)) >> 16;
    return (u16)r;
}
__device__ __forceinline__ float bf2f(u16 x) {
    union { uint32_t u; float f; } c; c.u = ((uint32_t)x) << 16;
    return c.f;
}

// async global->LDS, 16B per lane. LDS dest = wave-uniform base + lane*16.
__device__ __forceinline__ void async16(const void* g, void* l) {
    __builtin_amdgcn_global_load_lds(
        (const __attribute__((address_space(1))) uint32_t*)g,
        (__attribute__((address_space(3))) uint32_t*)l,
        16, 0, 0);
}

// 16x16x16 bf16 MFMA (legacy small-K shape; builtin name varies by ROCm)
__device__ __forceinline__ f32x4 pv_mfma(bf16x4 a, bf16x4 b, f32x4 c) {
#if __has_builtin(__builtin_amdgcn_mfma_f32_16x16x16_bf16)
    return __builtin_amdgcn_mfma_f32_16x16x16_bf16(a, b, c, 0, 0, 0);
#elif __has_builtin(__builtin_amdgcn_mfma_f32_16x16x16bf16_1k)
    typedef short s16x4 __attribute__((ext_vector_type(4)));
    union { bf16x4 h; s16x4 s; } ua, ub; ua.h = a; ub.h = b;
    return __builtin_amdgcn_mfma_f32_16x16x16bf16_1k(ua.s, ub.s, c, 0, 0, 0);
#else
    f32x4 d = c;
    asm("v_mfma_f32_16x16x16_bf16 %0, %1, %2, %0" : "+v"(d) : "v"(a), "v"(b));
    return d;
#endif
}

// ---------------- all weight transposes in ONE launch -----------------------
__global__ void transpose_all(const float* __restrict__ Wq, const float* __restrict__ Wk,
                              const float* __restrict__ Wv, const float* __restrict__ Wo,
                              const float* __restrict__ Wf1, const float* __restrict__ Wf2,
                              u16* __restrict__ wqkv, u16* __restrict__ wo,
                              u16* __restrict__ wf1, u16* __restrict__ wf2) {
    __shared__ float t[64][65];
    int bid = blockIdx.x;
    const float* src; u16* dst; int K, N, lb;
    if (bid < 256) {
        K = 512; N = 512;
        int which = bid >> 6; lb = bid & 63;
        src = which == 0 ? Wq : (which == 1 ? Wk : (which == 2 ? Wv : Wo));
        dst = which == 3 ? wo : wqkv + (size_t)which * 512 * 512;
    } else if (bid < 512) {
        K = 512; N = 2048; lb = bid - 256; src = Wf1; dst = wf1;
    } else {
        K = 2048; N = 512; lb = bid - 512; src = Wf2; dst = wf2;
    }
    const int nt = N / 64;
    const int k0 = (lb / nt) * 64, n0 = (lb % nt) * 64;
    const int c = threadIdx.x & 63, r0 = threadIdx.x >> 6;
#pragma unroll
    for (int i = 0; i < 16; ++i) {
        int r = r0 + i * 4;
        t[r][c] = src[(size_t)(k0 + r) * N + n0 + c];
    }
    __syncthreads();
#pragma unroll
    for (int i = 0; i < 16; ++i) {
        int r = r0 + i * 4;
        dst[(size_t)(n0 + r) * K + k0 + c] = f2bf(t[c][r]);
    }
}

// ---------------- adjacency -> bitmask (1 bit per entry) ---------------------
__global__ void pack_adj(const float* __restrict__ adj, u64* __restrict__ bits) {
    const int wid = blockIdx.x * 4 + (threadIdx.x >> 6);
    const int lane = threadIdx.x & 63;
    float v = adj[(size_t)wid * 64 + lane];
    u64 mask = __ballot(v > 0.5f);
    if (lane == 0) bits[wid] = mask;
}

// ---------------- LayerNorm over D=512, one wave per row --------------------
template <int BFIN>
__global__ void ln_kernel(const void* __restrict__ xv, const float* __restrict__ g,
                          const float* __restrict__ b, u16* __restrict__ out) {
    const int w = threadIdx.x >> 6, lane = threadIdx.x & 63;
    const int row = blockIdx.x * 4 + w;
    float f[8];
    if constexpr (BFIN) {
        const u16* xr = (const u16*)xv + (size_t)row * 512 + lane * 8;
        u16x8 v = *(const u16x8*)xr;
#pragma unroll
        for (int j = 0; j < 8; ++j) f[j] = bf2f(v[j]);
    } else {
        const float* xr = (const float*)xv + (size_t)row * 512 + lane * 8;
        float4 v0 = *(const float4*)xr;
        float4 v1 = *(const float4*)(xr + 4);
        f[0] = v0.x; f[1] = v0.y; f[2] = v0.z; f[3] = v0.w;
        f[4] = v1.x; f[5] = v1.y; f[6] = v1.z; f[7] = v1.w;
    }
    float sum = 0.f, sq = 0.f;
#pragma unroll
    for (int j = 0; j < 8; ++j) { sum += f[j]; sq += f[j] * f[j]; }
#pragma unroll
    for (int m = 1; m < 64; m <<= 1) {
        sum += __shfl_xor(sum, m);
        sq  += __shfl_xor(sq, m);
    }
    float mu = sum * (1.f / 512.f);
    float var = sq * (1.f / 512.f) - mu * mu;
    float rs = rsqrtf(var + 1e-5f);
    float4 g0 = *(const float4*)(g + lane * 8), g1 = *(const float4*)(g + lane * 8 + 4);
    float4 b0 = *(const float4*)(b + lane * 8), b1 = *(const float4*)(b + lane * 8 + 4);
    float gg[8] = {g0.x, g0.y, g0.z, g0.w, g1.x, g1.y, g1.z, g1.w};
    float bb[8] = {b0.x, b0.y, b0.z, b0.w, b1.x, b1.y, b1.z, b1.w};
    u16x8 o;
#pragma unroll
    for (int j = 0; j < 8; ++j) o[j] = f2bf((f[j] - mu) * rs * gg[j] + bb[j]);
    *(u16x8*)(out + (size_t)row * 512 + lane * 8) = o;
}

// ---------------- bf16 MFMA GEMM, C = A[M,K] @ Bt[N,K]^T, fused epilogues ---
// EPI 0: QKV (+bias): Q,K -> bf16 [B,H,N,64]; V -> TRANSPOSED vT [B,H,64,N]
// EPI 1: bf16 out = acc + b0[col] + addf32[row,col]         (stride 512)
// EPI 2: bf16 out = gelu(acc + b0[col])                     (stride 2048)
// EPI 3: f32 out  = acc + b0[col] + bf16(addbf[row,col])    (stride 512)
template <int WM, int WN, int EPI, int MINW>
__global__ __launch_bounds__(256, MINW)
void gemm_bt(const u16* __restrict__ A, const u16* __restrict__ Bt,
             int N, int K,
             const float* __restrict__ b0, const float* __restrict__ b1,
             const float* __restrict__ b2, const float* __restrict__ addf,
             const u16* __restrict__ addbf, float* __restrict__ outf,
             u16* __restrict__ o0, u16* __restrict__ o1, u16* __restrict__ o2) {
    constexpr int BM = 2 * WM, BN = 2 * WN;
    constexpr int MI = WM / 16, NI = WN / 16;
    constexpr int LA = BM / 32, LB = BN / 32;
    __shared__ __align__(16) u16 Als[BM * 64];
    __shared__ __align__(16) u16 Bls[BN * 64];
    const int tid = threadIdx.x, w = tid >> 6, lane = tid & 63;
    // XCD chunk swizzle (all grids %8==0)
    const int bid = ((int)blockIdx.x & 7) * ((int)gridDim.x >> 3) + ((int)blockIdx.x >> 3);
    const int nbn = N / BN;
    const int bm0 = (bid / nbn) * BM;
    const int bn0 = (bid % nbn) * BN;
    const int wr = w >> 1, wc = w & 1;
    const int srow = lane >> 3, schunk = lane & 7;
    f32x4 acc[MI][NI];
#pragma unroll
    for (int i = 0; i < MI; ++i)
#pragma unroll
        for (int j = 0; j < NI; ++j) acc[i][j] = f32x4{0.f, 0.f, 0.f, 0.f};

    for (int k0 = 0; k0 < K; k0 += 64) {
#pragma unroll
        for (int j = 0; j < LA; ++j) {
            int li = w * LA + j;
            int r = li * 8 + srow;
            async16(A + (size_t)(bm0 + r) * K + k0 + ((schunk ^ (r & 7)) << 3), &Als[li * 512]);
        }
#pragma unroll
        for (int j = 0; j < LB; ++j) {
            int li = w * LB + j;
            int r = li * 8 + srow;
            async16(Bt + (size_t)(bn0 + r) * K + k0 + ((schunk ^ (r & 7)) << 3), &Bls[li * 512]);
        }
        __syncthreads();
#pragma unroll
        for (int ks = 0; ks < 2; ++ks) {
            bf16x8 af[MI], bfr[NI];
            const int ck = ks * 4 + (lane >> 4);
#pragma unroll
            for (int mi = 0; mi < MI; ++mi) {
                int r = wr * WM + mi * 16 + (lane & 15);
                af[mi] = *(const bf16x8*)&Als[r * 64 + ((ck ^ (r & 7)) << 3)];
            }
#pragma unroll
            for (int ni = 0; ni < NI; ++ni) {
                int r = wc * WN + ni * 16 + (lane & 15);
                bfr[ni] = *(const bf16x8*)&Bls[r * 64 + ((ck ^ (r & 7)) << 3)];
            }
#pragma unroll
            for (int mi = 0; mi < MI; ++mi)
#pragma unroll
                for (int ni = 0; ni < NI; ++ni)
                    acc[mi][ni] = __builtin_amdgcn_mfma_f32_16x16x32_bf16(
                        af[mi], bfr[ni], acc[mi][ni], 0, 0, 0);
        }
        __syncthreads();
    }
#pragma unroll
    for (int mi = 0; mi < MI; ++mi)
#pragma unroll
        for (int ni = 0; ni < NI; ++ni)
#pragma unroll
            for (int reg = 0; reg < 4; ++reg) {
                int row = bm0 + wr * WM + mi * 16 + ((lane >> 4) << 2) + reg;
                int col = bn0 + wc * WN + ni * 16 + (lane & 15);
                float val = acc[mi][ni][reg];
                if constexpr (EPI == 0) {
                    int wsel = col >> 9, jj = col & 511;
                    const float* bb = wsel == 0 ? b0 : (wsel == 1 ? b1 : b2);
                    val += bb[jj];
                    int h = jj >> 6, hd = jj & 63;
                    int b_ = row >> 11, n_ = row & 2047;
                    if (wsel == 2) {  // V transposed: vT[(bh*64+hd)*2048 + n]
                        o2[(((size_t)(b_ * 8 + h) * 64 + hd) << 11) + n_] = f2bf(val);
                    } else {
                        u16* dst = wsel == 0 ? o0 : o1;
                        dst[(((size_t)(b_ * 8 + h) * 2048 + n_) << 6) + hd] = f2bf(val);
                    }
                } else if constexpr (EPI == 1) {
                    val += b0[col] + addf[(size_t)row * 512 + col];
                    o0[(size_t)row * 512 + col] = f2bf(val);
                } else if constexpr (EPI == 2) {
                    float x = val + b0[col];
                    float gx = 0.5f * x * (1.0f + erff(x * 0.70710678118654752f));
                    o0[(size_t)row * 2048 + col] = f2bf(gx);
                } else {
                    val += b0[col] + bf2f(addbf[(size_t)row * 512 + col]);
                    outf[(size_t)row * 512 + col] = val;
                }
            }
}

// ---------------- flash attention, 16x16 shapes, split-K over waves ---------
// grid: blockIdx = qt*32 + bh. block: 4 waves = (qg in {0,1}) x (ks in {0,1});
// wave (qg,ks) does q-rows [qt*64+qg*32, +32) vs keys [ks*1024, +1024).
// MFMA shapes: QK^T = 16x16x32 (S col=lane&15=q, row=(lane>>4)*4+reg=key);
// that S layout IS the 16x16x16 PV A-fragment (row=lane&15=q, k=(lane>>4)*4)
// -> no cross-lane shuffle between softmax and PV at all. Transients shrink
// (S=4 regs vs 16) so the live set (~100 VGPR) honestly fits the 128-reg cap
// of __launch_bounds__(256,4): 4 blocks/CU (LDS 33KB x4 = 133KB <= 160).
// Fixed-M softmax -> O,L pure sums; cross-ks combine exact via LDS at end.
// V pre-transposed by the QKV GEMM epilogue (vT[bh][hd][key]); staged via
// global_load_lds (pre-swizzled source, linear LDS dest), double-buffered.
// K direct global->reg (L2-hit).
__global__ __launch_bounds__(256, 4)
void attn16_kernel(const u16* __restrict__ q, const u16* __restrict__ k,
                   const u16* __restrict__ vT, const u64* __restrict__ adjbits,
                   u16* __restrict__ att) {
    const int tid = threadIdx.x, w = tid >> 6;
    const int lane = tid & 63, l15 = lane & 15, g4 = lane >> 4;
    const int qg = w >> 1, ks = w & 1;
    const int bh = blockIdx.x & 31, qt = blockIdx.x >> 5;
    const int b_ = bh >> 3, h_ = bh & 7;
    __shared__ __align__(16) u16 Vt[2][2][4096];   // [ks][buf][64 hd x 64 key], swizzled
    __shared__ float Lls[2][2][32];                // [qg][ks][qloc]
    const int q0 = qt * 64 + qg * 32;
    const u16* kbase = k + ((size_t)bh * 2048 + ks * 1024 + l15) * 64 + g4 * 8;
    const u64* adjr0 = adjbits + ((size_t)b_ * 2048 + q0 + l15) * 32 + ks * 16;
    const u64* adjr1 = adjr0 + 16 * 32;
    const int sr = lane >> 3, sc = lane & 7;
    const u16* vstage = vT + ((size_t)bh * 64 + qg * 32 + sr) * 2048 + ks * 1024 +
                        ((sc ^ sr) << 3);

    // Q fragments: Qf[qt2][c] = Q[q0+qt2*16+l15][c*32 + g4*8 ..+8]
    bf16x8 Qf[2][2];
#pragma unroll
    for (int qt2 = 0; qt2 < 2; ++qt2)
#pragma unroll
        for (int c = 0; c < 2; ++c)
            Qf[qt2][c] = *(const bf16x8*)(q + ((size_t)bh * 2048 + q0 + qt2 * 16 + l15) * 64
                                          + c * 32 + g4 * 8);
    f32x4 O0[4], O1[4];
#pragma unroll
    for (int t = 0; t < 4; ++t) { O0[t] = f32x4{0.f,0.f,0.f,0.f}; O1[t] = f32x4{0.f,0.f,0.f,0.f}; }
    float L0 = 0.f, L1 = 0.f;

    auto stage = [&](int it, int buf) {
#pragma unroll
        for (int j = 0; j < 4; ++j)
            async16(vstage + (size_t)j * 8 * 2048 + it * 64,
                    &Vt[ks][buf][(qg * 4 + j) * 512]);
    };
    stage(0, 0);
    __syncthreads();

    const int vx = l15 & 7;            // hd&7 for the V read swizzle
    for (int it = 0; it < 16; ++it) {
        const int cur = it & 1;
        if (it < 15) stage(it + 1, cur ^ 1);
        const u64 a0 = adjr0[it] >> (g4 * 4);
        const u64 a1 = adjr1[it] >> (g4 * 4);
        const char* vt = (const char*)&Vt[ks][cur][0];
#pragma unroll
        for (int st = 0; st < 4; ++st) {
            // K fragments for this 16-key subtile (row=l15=key, k-chunk=g4*8)
            bf16x8 Ka0 = *(const bf16x8*)(kbase + (size_t)(it * 64 + st * 16) * 64);
            bf16x8 Ka1 = *(const bf16x8*)(kbase + (size_t)(it * 64 + st * 16) * 64 + 32);
            f32x4 S0 = f32x4{0.f,0.f,0.f,0.f}, S1 = f32x4{0.f,0.f,0.f,0.f};
            __builtin_amdgcn_s_setprio(1);
            S0 = __builtin_amdgcn_mfma_f32_16x16x32_bf16(Ka0, Qf[0][0], S0, 0, 0, 0);
            S0 = __builtin_amdgcn_mfma_f32_16x16x32_bf16(Ka1, Qf[0][1], S0, 0, 0, 0);
            S1 = __builtin_amdgcn_mfma_f32_16x16x32_bf16(Ka0, Qf[1][0], S1, 0, 0, 0);
            S1 = __builtin_amdgcn_mfma_f32_16x16x32_bf16(Ka1, Qf[1][1], S1, 0, 0, 0);
            __builtin_amdgcn_s_setprio(0);
            // P = exp2(S*log2e/8 + cst(edge)); fixed offset M=12 (bounded logits;
            // uniform M cancels exactly in O/L)
            float p0[4], p1[4];
#pragma unroll
            for (int r_ = 0; r_ < 4; ++r_) {
                uint32_t e0 = (uint32_t)(a0 >> (st * 16 + r_)) & 1u;
                uint32_t e1 = (uint32_t)(a1 >> (st * 16 + r_)) & 1u;
                float c0 = e0 ? -15.8696454f : -20.7550354f;
                float c1 = e1 ? -15.8696454f : -20.7550354f;
                p0[r_] = __builtin_amdgcn_exp2f(S0[r_] * 0.18033688f + c0);
                p1[r_] = __builtin_amdgcn_exp2f(S1[r_] * 0.18033688f + c1);
            }
            L0 += (p0[0] + p0[1]) + (p0[2] + p0[3]);
            L1 += (p1[0] + p1[1]) + (p1[2] + p1[3]);
            bf16x4 pa0 = {(__bf16)p0[0], (__bf16)p0[1], (__bf16)p0[2], (__bf16)p0[3]};
            bf16x4 pa1 = {(__bf16)p1[0], (__bf16)p1[1], (__bf16)p1[2], (__bf16)p1[3]};
            // PV: bv = V[key st*16+g4*4 ..+4][hd t*16+l15] from swizzled LDS
            __builtin_amdgcn_s_setprio(1);
#pragma unroll
            for (int t = 0; t < 4; ++t) {
                int row = t * 16 + l15;
                int chunk = (st * 2 + (g4 >> 1)) ^ vx;
                bf16x4 bv = *(const bf16x4*)(vt + row * 128 + chunk * 16 + (g4 & 1) * 8);
                O0[t] = pv_mfma(pa0, bv, O0[t]);
                O1[t] = pv_mfma(pa1, bv, O1[t]);
            }
            __builtin_amdgcn_s_setprio(0);
        }
        __syncthreads();
    }

    // L reduce across g4 groups (lanes sharing l15)
    float Lt0 = L0 + __shfl_xor(L0, 16); Lt0 += __shfl_xor(Lt0, 32);
    float Lt1 = L1 + __shfl_xor(L1, 16); Lt1 += __shfl_xor(Lt1, 32);
    if (g4 == 0) {
        Lls[qg][ks][l15] = Lt0;
        Lls[qg][ks][16 + l15] = Lt1;
    }
    __syncthreads();
    // ks=1 publishes O (reuses Vt space), ks=0 combines + writes out
    float* Obuf = (float*)&Vt[0][0][0];  // [2 qg][32 qloc][64 hd] = 16 KB
    if (ks == 1) {
#pragma unroll
        for (int qt2 = 0; qt2 < 2; ++qt2)
#pragma unroll
            for (int t = 0; t < 4; ++t)
#pragma unroll
                for (int r_ = 0; r_ < 4; ++r_) {
                    int qloc = qt2 * 16 + g4 * 4 + r_;
                    int hd = t * 16 + l15;
                    float v = qt2 ? O1[t][r_] : O0[t][r_];
                    Obuf[((qg * 32 + qloc) << 6) + hd] = v;
                }
    }
    __syncthreads();
    if (ks == 0) {
        u16* outp = att + ((size_t)b_ * 2048 + q0) * 512 + (h_ << 6);
#pragma unroll
        for (int qt2 = 0; qt2 < 2; ++qt2)
#pragma unroll
            for (int t = 0; t < 4; ++t)
#pragma unroll
                for (int r_ = 0; r_ < 4; ++r_) {
                    int qloc = qt2 * 16 + g4 * 4 + r_;
                    int hd = t * 16 + l15;
                    float lsum = Lls[qg][0][qloc] + Lls[qg][1][qloc];
                    float inv = __builtin_amdgcn_rcpf(lsum);
                    float v = (qt2 ? O1[t][r_] : O0[t][r_]) +
                              Obuf[((qg * 32 + qloc) << 6) + hd];
                    outp[(size_t)qloc * 512 + hd] = f2bf(v * inv);
                }
    }
}

// ---------------------------------------------------------------------------
extern "C" void kernel_launch(void* const* d_in, const int* in_sizes, int n_in,
                              void* d_out, int out_size, void* d_ws, size_t ws_size,
                              hipStream_t stream) {
    const float* hidden = (const float*)d_in[0];
    const float* adj    = (const float*)d_in[1];
    const float* Wq = (const float*)d_in[2];
    const float* bq = (const float*)d_in[3];
    const float* Wk = (const float*)d_in[4];
    const float* bk = (const float*)d_in[5];
    const float* Wv = (const float*)d_in[6];
    const float* bv = (const float*)d_in[7];
    const float* Wo = (const float*)d_in[8];
    const float* bo = (const float*)d_in[9];
    const float* g1 = (const float*)d_in[10];
    const float* b1 = (const float*)d_in[11];
    const float* g2 = (const float*)d_in[12];
    const float* b2 = (const float*)d_in[13];
    const float* Wf1 = (const float*)d_in[14];
    const float* bf1 = (const float*)d_in[15];
    const float* Wf2 = (const float*)d_in[16];
    const float* bf2 = (const float*)d_in[17];
    float* out = (float*)d_out;

    char* p = (char*)d_ws;
    u16* wqkv_t = (u16*)p; p += (size_t)1536 * 512 * 2;
    u16* wo_t   = (u16*)p; p += (size_t)512 * 512 * 2;
    u16* wf1_t  = (u16*)p; p += (size_t)2048 * 512 * 2;
    u16* wf2_t  = (u16*)p; p += (size_t)512 * 2048 * 2;
    u64* adjbits = (u64*)p; p += (size_t)4 * 2048 * 32 * 8;
    u16* bufA = (u16*)p; p += (size_t)8192 * 512 * 2;   // normed, then attended
    u16* bufQ = (u16*)p; p += (size_t)8192 * 512 * 2;   // q, then h2
    float* midreg = (float*)p; p += (size_t)8192 * 512 * 4;  // vT | mid(bf16)
    u16* kbuf = (u16*)p; p += (size_t)8192 * 512 * 2;
    u16* vbuf = (u16*)p; p += (size_t)8192 * 512 * 2;   // (unused; part of ffh span)
    p += (size_t)16 * 1024 * 1024;                       // ffh tail
    u16* ffh = kbuf;  // 8192*2048 bf16 spans kbuf+vbuf+tail (dead after attention)
    u16* vT  = (u16*)midreg;                      // [32 bh][64 hd][2048 key] bf16
    u16* mid = (u16*)midreg + (size_t)8192 * 512; // bf16 mid (disjoint half)
    (void)vbuf; (void)ws_size; (void)in_sizes; (void)n_in; (void)out_size;

    transpose_all<<<768, 256, 0, stream>>>(Wq, Wk, Wv, Wo, Wf1, Wf2,
                                           wqkv_t, wo_t, wf1_t, wf2_t);
    pack_adj<<<65536, 256, 0, stream>>>(adj, adjbits);
    ln_kernel<0><<<2048, 256, 0, stream>>>(hidden, g1, b1, bufA);
    // QKV: Q,K scattered [B,H,N,64]; V written directly TRANSPOSED into vT
    gemm_bt<64, 64, 0, 3><<<64 * 12, 256, 0, stream>>>(bufA, wqkv_t, 1536, 512,
        bq, bk, bv, nullptr, nullptr, nullptr, bufQ, kbuf, vT);
    attn16_kernel<<<1024, 256, 0, stream>>>(bufQ, kbuf, vT, adjbits, bufA);
    // Wo + bias + residual(hidden f32) -> mid (bf16)
    gemm_bt<32, 64, 1, 4><<<512, 256, 0, stream>>>(bufA, wo_t, 512, 512,
        bo, nullptr, nullptr, hidden, nullptr, nullptr, mid, nullptr, nullptr);
    ln_kernel<1><<<2048, 256, 0, stream>>>(mid, g2, b2, bufQ);
    gemm_bt<64, 64, 2, 3><<<64 * 16, 256, 0, stream>>>(bufQ, wf1_t, 2048, 512,
        bf1, nullptr, nullptr, nullptr, nullptr, nullptr, ffh, nullptr, nullptr);
    // FF2 + bias + residual(mid bf16) -> out (f32)
    gemm_bt<32, 64, 3, 4><<<512, 256, 0, stream>>>(ffh, wf2_t, 512, 2048,
        bf2, nullptr, nullptr, nullptr, mid, out, nullptr, nullptr, nullptr);
}

// Round 11
// 232.882 us; speedup vs baseline: 1.1671x; 1.1671x over previous
//
#include <hip/hip_runtime.h>
#include <stdint.h>

typedef unsigned short u16;
typedef unsigned long long u64;
typedef __bf16 bf16x8 __attribute__((ext_vector_type(8)));
typedef float f32x4 __attribute__((ext_vector_type(4)));
typedef float f32x16 __attribute__((ext_vector_type(16)));
typedef u16 u16x8 __attribute__((ext_vector_type(8)));

// f32 -> bf16 round-to-nearest-even (branchless; inputs finite)
__device__ __forceinline__ u16 f2bf(float x) {
    union { float f; uint32_t u; } c; c.f = x;
    uint32_t r = (c.u + 0x7fffu + ((c.u >> 16) & 1u)) >> 16;
    return (u16)r;
}
__device__ __forceinline__ float bf2f(u16 x) {
    union { uint32_t u; float f; } c; c.u = ((uint32_t)x) << 16;
    return c.f;
}

// async global->LDS, 16B per lane. LDS dest = wave-uniform base + lane*16.
__device__ __forceinline__ void async16(const void* g, void* l) {
    __builtin_amdgcn_global_load_lds(
        (const __attribute__((address_space(1))) uint32_t*)g,
        (__attribute__((address_space(3))) uint32_t*)l,
        16, 0, 0);
}

// v_permlane32_swap_b32: a' = [a_lo, b_lo(from partner)], b' = [a_hi(from partner), b_hi]
__device__ __forceinline__ void permswap(uint32_t& a, uint32_t& b) {
    asm volatile("v_permlane32_swap_b32 %0, %1" : "+v"(a), "+v"(b));
}

// ---------------- all weight transposes in ONE launch -----------------------
__global__ void transpose_all(const float* __restrict__ Wq, const float* __restrict__ Wk,
                              const float* __restrict__ Wv, const float* __restrict__ Wo,
                              const float* __restrict__ Wf1, const float* __restrict__ Wf2,
                              u16* __restrict__ wqkv, u16* __restrict__ wo,
                              u16* __restrict__ wf1, u16* __restrict__ wf2) {
    __shared__ float t[64][65];
    int bid = blockIdx.x;
    const float* src; u16* dst; int K, N, lb;
    if (bid < 256) {
        K = 512; N = 512;
        int which = bid >> 6; lb = bid & 63;
        src = which == 0 ? Wq : (which == 1 ? Wk : (which == 2 ? Wv : Wo));
        dst = which == 3 ? wo : wqkv + (size_t)which * 512 * 512;
    } else if (bid < 512) {
        K = 512; N = 2048; lb = bid - 256; src = Wf1; dst = wf1;
    } else {
        K = 2048; N = 512; lb = bid - 512; src = Wf2; dst = wf2;
    }
    const int nt = N / 64;
    const int k0 = (lb / nt) * 64, n0 = (lb % nt) * 64;
    const int c = threadIdx.x & 63, r0 = threadIdx.x >> 6;
#pragma unroll
    for (int i = 0; i < 16; ++i) {
        int r = r0 + i * 4;
        t[r][c] = src[(size_t)(k0 + r) * N + n0 + c];
    }
    __syncthreads();
#pragma unroll
    for (int i = 0; i < 16; ++i) {
        int r = r0 + i * 4;
        dst[(size_t)(n0 + r) * K + k0 + c] = f2bf(t[c][r]);
    }
}

// ---------------- adjacency -> bitmask (1 bit per entry) ---------------------
__global__ void pack_adj(const float* __restrict__ adj, u64* __restrict__ bits) {
    const int wid = blockIdx.x * 4 + (threadIdx.x >> 6);
    const int lane = threadIdx.x & 63;
    float v = adj[(size_t)wid * 64 + lane];
    u64 mask = __ballot(v > 0.5f);
    if (lane == 0) bits[wid] = mask;
}

// ---------------- LayerNorm over D=512, one wave per row --------------------
template <int BFIN>
__global__ void ln_kernel(const void* __restrict__ xv, const float* __restrict__ g,
                          const float* __restrict__ b, u16* __restrict__ out) {
    const int w = threadIdx.x >> 6, lane = threadIdx.x & 63;
    const int row = blockIdx.x * 4 + w;
    float f[8];
    if constexpr (BFIN) {
        const u16* xr = (const u16*)xv + (size_t)row * 512 + lane * 8;
        u16x8 v = *(const u16x8*)xr;
#pragma unroll
        for (int j = 0; j < 8; ++j) f[j] = bf2f(v[j]);
    } else {
        const float* xr = (const float*)xv + (size_t)row * 512 + lane * 8;
        float4 v0 = *(const float4*)xr;
        float4 v1 = *(const float4*)(xr + 4);
        f[0] = v0.x; f[1] = v0.y; f[2] = v0.z; f[3] = v0.w;
        f[4] = v1.x; f[5] = v1.y; f[6] = v1.z; f[7] = v1.w;
    }
    float sum = 0.f, sq = 0.f;
#pragma unroll
    for (int j = 0; j < 8; ++j) { sum += f[j]; sq += f[j] * f[j]; }
#pragma unroll
    for (int m = 1; m < 64; m <<= 1) {
        sum += __shfl_xor(sum, m);
        sq  += __shfl_xor(sq, m);
    }
    float mu = sum * (1.f / 512.f);
    float var = sq * (1.f / 512.f) - mu * mu;
    float rs = rsqrtf(var + 1e-5f);
    float4 g0 = *(const float4*)(g + lane * 8), g1 = *(const float4*)(g + lane * 8 + 4);
    float4 b0 = *(const float4*)(b + lane * 8), b1 = *(const float4*)(b + lane * 8 + 4);
    float gg[8] = {g0.x, g0.y, g0.z, g0.w, g1.x, g1.y, g1.z, g1.w};
    float bb[8] = {b0.x, b0.y, b0.z, b0.w, b1.x, b1.y, b1.z, b1.w};
    u16x8 o;
#pragma unroll
    for (int j = 0; j < 8; ++j) o[j] = f2bf((f[j] - mu) * rs * gg[j] + bb[j]);
    *(u16x8*)(out + (size_t)row * 512 + lane * 8) = o;
}

// ---------------- bf16 MFMA GEMM, C = A[M,K] @ Bt[N,K]^T, fused epilogues ---
// EPI 0: QKV (+bias): Q,K -> bf16 [B,H,N,64]; V -> TRANSPOSED vT [B,H,64,N]
// EPI 1: bf16 out = acc + b0[col] + addf32[row,col]         (stride 512)
// EPI 2: bf16 out = gelu(acc + b0[col])                     (stride 2048)
// EPI 3: f32 out  = acc + b0[col] + bf16(addbf[row,col])    (stride 512)
template <int WM, int WN, int EPI, int MINW>
__global__ __launch_bounds__(256, MINW)
void gemm_bt(const u16* __restrict__ A, const u16* __restrict__ Bt,
             int N, int K,
             const float* __restrict__ b0, const float* __restrict__ b1,
             const float* __restrict__ b2, const float* __restrict__ addf,
             const u16* __restrict__ addbf, float* __restrict__ outf,
             u16* __restrict__ o0, u16* __restrict__ o1, u16* __restrict__ o2) {
    constexpr int BM = 2 * WM, BN = 2 * WN;
    constexpr int MI = WM / 16, NI = WN / 16;
    constexpr int LA = BM / 32, LB = BN / 32;
    __shared__ __align__(16) u16 Als[BM * 64];
    __shared__ __align__(16) u16 Bls[BN * 64];
    const int tid = threadIdx.x, w = tid >> 6, lane = tid & 63;
    // XCD chunk swizzle (all grids %8==0)
    const int bid = ((int)blockIdx.x & 7) * ((int)gridDim.x >> 3) + ((int)blockIdx.x >> 3);
    const int nbn = N / BN;
    const int bm0 = (bid / nbn) * BM;
    const int bn0 = (bid % nbn) * BN;
    const int wr = w >> 1, wc = w & 1;
    const int srow = lane >> 3, schunk = lane & 7;
    f32x4 acc[MI][NI];
#pragma unroll
    for (int i = 0; i < MI; ++i)
#pragma unroll
        for (int j = 0; j < NI; ++j) acc[i][j] = f32x4{0.f, 0.f, 0.f, 0.f};

    for (int k0 = 0; k0 < K; k0 += 64) {
#pragma unroll
        for (int j = 0; j < LA; ++j) {
            int li = w * LA + j;
            int r = li * 8 + srow;
            async16(A + (size_t)(bm0 + r) * K + k0 + ((schunk ^ (r & 7)) << 3), &Als[li * 512]);
        }
#pragma unroll
        for (int j = 0; j < LB; ++j) {
            int li = w * LB + j;
            int r = li * 8 + srow;
            async16(Bt + (size_t)(bn0 + r) * K + k0 + ((schunk ^ (r & 7)) << 3), &Bls[li * 512]);
        }
        __syncthreads();
#pragma unroll
        for (int ks = 0; ks < 2; ++ks) {
            bf16x8 af[MI], bfr[NI];
            const int ck = ks * 4 + (lane >> 4);
#pragma unroll
            for (int mi = 0; mi < MI; ++mi) {
                int r = wr * WM + mi * 16 + (lane & 15);
                af[mi] = *(const bf16x8*)&Als[r * 64 + ((ck ^ (r & 7)) << 3)];
            }
#pragma unroll
            for (int ni = 0; ni < NI; ++ni) {
                int r = wc * WN + ni * 16 + (lane & 15);
                bfr[ni] = *(const bf16x8*)&Bls[r * 64 + ((ck ^ (r & 7)) << 3)];
            }
#pragma unroll
            for (int mi = 0; mi < MI; ++mi)
#pragma unroll
                for (int ni = 0; ni < NI; ++ni)
                    acc[mi][ni] = __builtin_amdgcn_mfma_f32_16x16x32_bf16(
                        af[mi], bfr[ni], acc[mi][ni], 0, 0, 0);
        }
        __syncthreads();
    }
#pragma unroll
    for (int mi = 0; mi < MI; ++mi)
#pragma unroll
        for (int ni = 0; ni < NI; ++ni)
#pragma unroll
            for (int reg = 0; reg < 4; ++reg) {
                int row = bm0 + wr * WM + mi * 16 + ((lane >> 4) << 2) + reg;
                int col = bn0 + wc * WN + ni * 16 + (lane & 15);
                float val = acc[mi][ni][reg];
                if constexpr (EPI == 0) {
                    int wsel = col >> 9, jj = col & 511;
                    const float* bb = wsel == 0 ? b0 : (wsel == 1 ? b1 : b2);
                    val += bb[jj];
                    int h = jj >> 6, hd = jj & 63;
                    int b_ = row >> 11, n_ = row & 2047;
                    if (wsel == 2) {  // V transposed: vT[(bh*64+hd)*2048 + n]
                        o2[(((size_t)(b_ * 8 + h) * 64 + hd) << 11) + n_] = f2bf(val);
                    } else {
                        u16* dst = wsel == 0 ? o0 : o1;
                        dst[(((size_t)(b_ * 8 + h) * 2048 + n_) << 6) + hd] = f2bf(val);
                    }
                } else if constexpr (EPI == 1) {
                    val += b0[col] + addf[(size_t)row * 512 + col];
                    o0[(size_t)row * 512 + col] = f2bf(val);
                } else if constexpr (EPI == 2) {
                    float x = val + b0[col];
                    float gx = 0.5f * x * (1.0f + erff(x * 0.70710678118654752f));
                    o0[(size_t)row * 2048 + col] = f2bf(gx);
                } else {
                    val += b0[col] + bf2f(addbf[(size_t)row * 512 + col]);
                    outf[(size_t)row * 512 + col] = val;
                }
            }
}

// ---------------- flash attention, swapped-QK^T, split-K over waves ---------
// R9 configuration (best measured: 92.6us). grid: blockIdx = qt*32 + bh.
// block: 4 waves = (qg in {0,1}) x (ks in {0,1}); wave (qg,ks) does q-rows
// [qt*64+qg*32, +32) against keys [ks*1024, +1024). Fixed-M softmax -> O,L are
// pure sums; cross-ks combine is exact addition via LDS at the end.
// V pre-transposed (vT[bh][hd][key]) by the QKV GEMM epilogue; staged via
// global_load_lds (pre-swizzled source, linear LDS dest), double-buffered.
// K direct global->reg (L2-hit).
// __launch_bounds__(256,3): live set ~140 VGPR; the 128-reg cap of minw=4
// spills to scratch (R3/R5/R8/R10: WRITE_SIZE 35-600MB), spill >> occupancy.
__global__ __launch_bounds__(256, 3)
void attn32_kernel(const u16* __restrict__ q, const u16* __restrict__ k,
                   const u16* __restrict__ vT, const u64* __restrict__ adjbits,
                   u16* __restrict__ att) {
    const int tid = threadIdx.x, w = tid >> 6;
    const int lane = tid & 63, col = lane & 31, g = lane >> 5;
    const int qg = w >> 1, ks = w & 1;
    const int bh = blockIdx.x & 31, qt = blockIdx.x >> 5;
    const int b_ = bh >> 3, h_ = bh & 7;
    __shared__ __align__(16) u16 Vt[2][2][4096];   // [ks][buf][64 hd x 64 key], swizzled
    __shared__ float Lls[2][2][32];                // [qg][ks][q]
    const int q0 = qt * 64 + qg * 32;
    const int myq = q0 + col;
    const u16* qptr = q + ((size_t)bh * 2048 + myq) * 64 + g * 8;
    const u16* kptr = k + ((size_t)bh * 2048 + ks * 1024 + col) * 64 + g * 8;
    const u64* adjrow = adjbits + ((size_t)b_ * 2048 + myq) * 32 + ks * 16;
    // staging source: lane covers row r = qg*32 + j*8 + (lane>>3), chunk c = lane&7
    const int sr = lane >> 3, sc = lane & 7;
    const u16* vstage = vT + ((size_t)bh * 64 + qg * 32 + sr) * 2048 + ks * 1024 +
                        ((sc ^ sr) << 3);

    bf16x8 Qf[4];
#pragma unroll
    for (int c = 0; c < 4; ++c) Qf[c] = *(const bf16x8*)(qptr + c * 16);
    f32x16 O0, O1;
#pragma unroll
    for (int i = 0; i < 16; ++i) { O0[i] = 0.f; O1[i] = 0.f; }
    float L = 0.f;

    auto stage = [&](int it, int buf) {
#pragma unroll
        for (int j = 0; j < 4; ++j)
            async16(vstage + (size_t)j * 8 * 2048 + it * 64,
                    &Vt[ks][buf][(qg * 4 + j) * 512]);
    };
    stage(0, 0);
    __syncthreads();

    for (int it = 0; it < 16; ++it) {
        const int cur = it & 1;
        if (it < 15) stage(it + 1, cur ^ 1);
        const u64 adjw = adjrow[it];
        const char* vt = (const char*)&Vt[ks][cur][0];
#pragma unroll
        for (int s = 0; s < 2; ++s) {
            bf16x8 Ku[4];
#pragma unroll
            for (int c = 0; c < 4; ++c)
                Ku[c] = *(const bf16x8*)(kptr + (size_t)(it * 64 + s * 32) * 64 + c * 16);
            f32x16 S;
#pragma unroll
            for (int i = 0; i < 16; ++i) S[i] = 0.f;
            __builtin_amdgcn_s_setprio(1);
#pragma unroll
            for (int c = 0; c < 4; ++c)
                S = __builtin_amdgcn_mfma_f32_32x32x16_bf16(Ku[c], Qf[c], S, 0, 0, 0);
            __builtin_amdgcn_s_setprio(0);
            uint32_t w32 = (uint32_t)(adjw >> (32 * s));
            // P = exp2(S*log2e/8 + cst(edge)); fixed offset M=12 (no online max:
            // masked logits bounded; uniform M cancels exactly in O/L)
            float p[16];
#pragma unroll
            for (int r_ = 0; r_ < 16; ++r_) {
                int bit = (r_ & 3) + 8 * (r_ >> 2) + 4 * g;
                float cst = ((w32 >> bit) & 1u) ? -15.8696454f : -20.7550354f;
                p[r_] = __builtin_amdgcn_exp2f(S[r_] * 0.18033688f + cst);
            }
            float t0 = (p[0] + p[1]) + (p[2] + p[3]);
            float t1 = (p[4] + p[5]) + (p[6] + p[7]);
            float t2s = (p[8] + p[9]) + (p[10] + p[11]);
            float t3 = (p[12] + p[13]) + (p[14] + p[15]);
            L += (t0 + t1) + (t2s + t3);
            // pack to bf16 + permlane redistribution -> PV A-fragments
            uint32_t pk[8];
#pragma unroll
            for (int i = 0; i < 8; ++i) {
                union { __bf16 h[2]; uint32_t u; } pu;
                pu.h[0] = (__bf16)p[2 * i]; pu.h[1] = (__bf16)p[2 * i + 1];
                pk[i] = pu.u;
            }
            permswap(pk[0], pk[2]); permswap(pk[1], pk[3]);
            permswap(pk[4], pk[6]); permswap(pk[5], pk[7]);
            union { uint32_t u[4]; bf16x8 v; } fa0, fa1;
            fa0.u[0] = pk[0]; fa0.u[1] = pk[1]; fa0.u[2] = pk[2]; fa0.u[3] = pk[3];
            fa1.u[0] = pk[4]; fa1.u[1] = pk[5]; fa1.u[2] = pk[6]; fa1.u[3] = pk[7];
            __builtin_amdgcn_s_setprio(1);
#pragma unroll
            for (int c2 = 0; c2 < 2; ++c2) {
                int kb = (s * 32 + c2 * 16 + g * 8) * 2;
                int r0 = col, r1 = 32 + col;
                bf16x8 fv0 = *(const bf16x8*)(vt + ((r0 * 128 + kb) ^ ((r0 & 7) << 4)));
                bf16x8 fv1 = *(const bf16x8*)(vt + ((r1 * 128 + kb) ^ ((r1 & 7) << 4)));
                const bf16x8 fa = c2 ? fa1.v : fa0.v;
                O0 = __builtin_amdgcn_mfma_f32_32x32x16_bf16(fa, fv0, O0, 0, 0, 0);
                O1 = __builtin_amdgcn_mfma_f32_32x32x16_bf16(fa, fv1, O1, 0, 0, 0);
            }
            __builtin_amdgcn_s_setprio(0);
        }
        __syncthreads();
    }

    // cross-g L merge (per q-col), publish per-(qg,ks) L
    float Lt = L + __shfl_xor(L, 32);
    if (g == 0) Lls[qg][ks][col] = Lt;
    __syncthreads();
    // ks=1 publishes O into LDS (reuses Vt space), ks=0 combines + writes out
    float* Obuf = (float*)&Vt[0][0][0];  // [2 qg][32 q][64 hd]
    if (ks == 1) {
#pragma unroll
        for (int r_ = 0; r_ < 16; ++r_) {
            int qrow = (r_ & 3) + 8 * (r_ >> 2) + 4 * g;
            Obuf[((qg * 32 + qrow) << 6) + col] = O0[r_];
            Obuf[((qg * 32 + qrow) << 6) + 32 + col] = O1[r_];
        }
    }
    __syncthreads();
    if (ks == 0) {
        u16* outp = att + ((size_t)b_ * 2048 + q0) * 512 + (h_ << 6);
#pragma unroll
        for (int r_ = 0; r_ < 16; ++r_) {
            int qrow = (r_ & 3) + 8 * (r_ >> 2) + 4 * g;
            float lsum = Lls[qg][0][qrow] + Lls[qg][1][qrow];
            float inv = __builtin_amdgcn_rcpf(lsum);
            float o0 = O0[r_] + Obuf[((qg * 32 + qrow) << 6) + col];
            float o1 = O1[r_] + Obuf[((qg * 32 + qrow) << 6) + 32 + col];
            outp[(size_t)qrow * 512 + col] = f2bf(o0 * inv);
            outp[(size_t)qrow * 512 + 32 + col] = f2bf(o1 * inv);
        }
    }
}

// ---------------------------------------------------------------------------
extern "C" void kernel_launch(void* const* d_in, const int* in_sizes, int n_in,
                              void* d_out, int out_size, void* d_ws, size_t ws_size,
                              hipStream_t stream) {
    const float* hidden = (const float*)d_in[0];
    const float* adj    = (const float*)d_in[1];
    const float* Wq = (const float*)d_in[2];
    const float* bq = (const float*)d_in[3];
    const float* Wk = (const float*)d_in[4];
    const float* bk = (const float*)d_in[5];
    const float* Wv = (const float*)d_in[6];
    const float* bv = (const float*)d_in[7];
    const float* Wo = (const float*)d_in[8];
    const float* bo = (const float*)d_in[9];
    const float* g1 = (const float*)d_in[10];
    const float* b1 = (const float*)d_in[11];
    const float* g2 = (const float*)d_in[12];
    const float* b2 = (const float*)d_in[13];
    const float* Wf1 = (const float*)d_in[14];
    const float* bf1 = (const float*)d_in[15];
    const float* Wf2 = (const float*)d_in[16];
    const float* bf2 = (const float*)d_in[17];
    float* out = (float*)d_out;

    char* p = (char*)d_ws;
    u16* wqkv_t = (u16*)p; p += (size_t)1536 * 512 * 2;
    u16* wo_t   = (u16*)p; p += (size_t)512 * 512 * 2;
    u16* wf1_t  = (u16*)p; p += (size_t)2048 * 512 * 2;
    u16* wf2_t  = (u16*)p; p += (size_t)512 * 2048 * 2;
    u64* adjbits = (u64*)p; p += (size_t)4 * 2048 * 32 * 8;
    u16* bufA = (u16*)p; p += (size_t)8192 * 512 * 2;   // normed, then attended
    u16* bufQ = (u16*)p; p += (size_t)8192 * 512 * 2;   // q, then h2
    float* midreg = (float*)p; p += (size_t)8192 * 512 * 4;  // vT | mid(bf16)
    u16* kbuf = (u16*)p; p += (size_t)8192 * 512 * 2;
    u16* vbuf = (u16*)p; p += (size_t)8192 * 512 * 2;   // (part of ffh span)
    p += (size_t)16 * 1024 * 1024;                       // ffh tail
    u16* ffh = kbuf;  // 8192*2048 bf16 spans kbuf+vbuf+tail (dead after attention)
    u16* vT  = (u16*)midreg;                      // [32 bh][64 hd][2048 key] bf16
    u16* mid = (u16*)midreg + (size_t)8192 * 512; // bf16 mid (disjoint half)
    (void)vbuf; (void)ws_size; (void)in_sizes; (void)n_in; (void)out_size;

    transpose_all<<<768, 256, 0, stream>>>(Wq, Wk, Wv, Wo, Wf1, Wf2,
                                           wqkv_t, wo_t, wf1_t, wf2_t);
    pack_adj<<<65536, 256, 0, stream>>>(adj, adjbits);
    ln_kernel<0><<<2048, 256, 0, stream>>>(hidden, g1, b1, bufA);
    // QKV: Q,K scattered [B,H,N,64]; V written directly TRANSPOSED into vT
    gemm_bt<64, 64, 0, 3><<<64 * 12, 256, 0, stream>>>(bufA, wqkv_t, 1536, 512,
        bq, bk, bv, nullptr, nullptr, nullptr, bufQ, kbuf, vT);
    attn32_kernel<<<1024, 256, 0, stream>>>(bufQ, kbuf, vT, adjbits, bufA);
    // Wo + bias + residual(hidden f32) -> mid (bf16)
    gemm_bt<32, 64, 1, 4><<<512, 256, 0, stream>>>(bufA, wo_t, 512, 512,
        bo, nullptr, nullptr, hidden, nullptr, nullptr, mid, nullptr, nullptr);
    ln_kernel<1><<<2048, 256, 0, stream>>>(mid, g2, b2, bufQ);
    gemm_bt<64, 64, 2, 3><<<64 * 16, 256, 0, stream>>>(bufQ, wf1_t, 2048, 512,
        bf1, nullptr, nullptr, nullptr, nullptr, nullptr, ffh, nullptr, nullptr);
    // FF2 + bias + residual(mid bf16) -> out (f32)
    gemm_bt<32, 64, 3, 4><<<512, 256, 0, stream>>>(ffh, wf2_t, 512, 2048,
        bf2, nullptr, nullptr, nullptr, mid, out, nullptr, nullptr, nullptr);
}

// Round 12
// 210.582 us; speedup vs baseline: 1.2907x; 1.1059x over previous
//
#include <hip/hip_runtime.h>
#include <stdint.h>

typedef unsigned short u16;
typedef unsigned long long u64;
typedef __bf16 bf16x8 __attribute__((ext_vector_type(8)));
typedef float f32x4 __attribute__((ext_vector_type(4)));
typedef float f32x16 __attribute__((ext_vector_type(16)));
typedef u16 u16x8 __attribute__((ext_vector_type(8)));

// f32 -> bf16 round-to-nearest-even (branchless; inputs finite)
__device__ __forceinline__ u16 f2bf(float x) {
    union { float f; uint32_t u; } c; c.f = x;
    uint32_t r = (c.u + 0x7fffu + ((c.u >> 16) & 1u)) >> 16;
    return (u16)r;
}
__device__ __forceinline__ float bf2f(u16 x) {
    union { uint32_t u; float f; } c; c.u = ((uint32_t)x) << 16;
    return c.f;
}

// async global->LDS, 16B per lane. LDS dest = wave-uniform base + lane*16.
__device__ __forceinline__ void async16(const void* g, void* l) {
    __builtin_amdgcn_global_load_lds(
        (const __attribute__((address_space(1))) uint32_t*)g,
        (__attribute__((address_space(3))) uint32_t*)l,
        16, 0, 0);
}

// v_permlane32_swap_b32: a' = [a_lo, b_lo(from partner)], b' = [a_hi(from partner), b_hi]
__device__ __forceinline__ void permswap(uint32_t& a, uint32_t& b) {
    asm volatile("v_permlane32_swap_b32 %0, %1" : "+v"(a), "+v"(b));
}

// ---------------- merged prep: weight transposes + adj bitmask + LN1 --------
// block ranges: [0,768)   weight transposes (Wq/Wk/Wv/Wo/Wf1/Wf2 -> bf16 B^T)
//               [768,2816)  adjacency -> bitmask (vectorized, 4 words/wave/step)
//               [2816,4864) LayerNorm1 (f32 in -> bf16 out), 4 rows/block
__global__ void prep_kernel(const float* __restrict__ Wq, const float* __restrict__ Wk,
                            const float* __restrict__ Wv, const float* __restrict__ Wo,
                            const float* __restrict__ Wf1, const float* __restrict__ Wf2,
                            const float* __restrict__ adj, const float* __restrict__ hidden,
                            const float* __restrict__ g1, const float* __restrict__ b1,
                            u16* __restrict__ wqkv, u16* __restrict__ wo,
                            u16* __restrict__ wf1, u16* __restrict__ wf2,
                            u64* __restrict__ bits, u16* __restrict__ ln1out) {
    __shared__ float t[64][65];
    const int bid = blockIdx.x, tid = threadIdx.x;
    if (bid < 768) {
        const float* src; u16* dst; int K, N, lb;
        if (bid < 256) {
            K = 512; N = 512;
            int which = bid >> 6; lb = bid & 63;
            src = which == 0 ? Wq : (which == 1 ? Wk : (which == 2 ? Wv : Wo));
            dst = which == 3 ? wo : wqkv + (size_t)which * 512 * 512;
        } else if (bid < 512) {
            K = 512; N = 2048; lb = bid - 256; src = Wf1; dst = wf1;
        } else {
            K = 2048; N = 512; lb = bid - 512; src = Wf2; dst = wf2;
        }
        const int nt = N / 64;
        const int k0 = (lb / nt) * 64, n0 = (lb % nt) * 64;
        const int c = tid & 63, r0 = tid >> 6;
#pragma unroll
        for (int i = 0; i < 16; ++i) {
            int r = r0 + i * 4;
            t[r][c] = src[(size_t)(k0 + r) * N + n0 + c];
        }
        __syncthreads();
#pragma unroll
        for (int i = 0; i < 16; ++i) {
            int r = r0 + i * 4;
            dst[(size_t)(n0 + r) * K + k0 + c] = f2bf(t[c][r]);
        }
    } else if (bid < 2816) {
        // adjacency pack: 262144 u64 words total; 8192 waves x 32 words each
        const int wv = (bid - 768) * 4 + (tid >> 6), lane = tid & 63;
        const size_t wbase = (size_t)wv * 32;
#pragma unroll
        for (int s = 0; s < 8; ++s) {
            size_t w0 = wbase + s * 4;
            const float* fp = adj + w0 * 64 + lane;
            u64 m0 = __ballot(fp[0]   > 0.5f);
            u64 m1 = __ballot(fp[64]  > 0.5f);
            u64 m2 = __ballot(fp[128] > 0.5f);
            u64 m3 = __ballot(fp[192] > 0.5f);
            if (lane == 0) {
                bits[w0] = m0; bits[w0 + 1] = m1; bits[w0 + 2] = m2; bits[w0 + 3] = m3;
            }
        }
    } else {
        const int w = tid >> 6, lane = tid & 63;
        const int row = (bid - 2816) * 4 + w;
        const float* xr = hidden + (size_t)row * 512 + lane * 8;
        float4 v0 = *(const float4*)xr;
        float4 v1 = *(const float4*)(xr + 4);
        float f[8] = {v0.x, v0.y, v0.z, v0.w, v1.x, v1.y, v1.z, v1.w};
        float sum = 0.f, sq = 0.f;
#pragma unroll
        for (int j = 0; j < 8; ++j) { sum += f[j]; sq += f[j] * f[j]; }
#pragma unroll
        for (int m = 1; m < 64; m <<= 1) {
            sum += __shfl_xor(sum, m);
            sq  += __shfl_xor(sq, m);
        }
        float mu = sum * (1.f / 512.f);
        float var = sq * (1.f / 512.f) - mu * mu;
        float rs = rsqrtf(var + 1e-5f);
        float4 g0 = *(const float4*)(g1 + lane * 8), gg1 = *(const float4*)(g1 + lane * 8 + 4);
        float4 bb0 = *(const float4*)(b1 + lane * 8), bb1 = *(const float4*)(b1 + lane * 8 + 4);
        float gg[8] = {g0.x, g0.y, g0.z, g0.w, gg1.x, gg1.y, gg1.z, gg1.w};
        float bb[8] = {bb0.x, bb0.y, bb0.z, bb0.w, bb1.x, bb1.y, bb1.z, bb1.w};
        u16x8 o;
#pragma unroll
        for (int j = 0; j < 8; ++j) o[j] = f2bf((f[j] - mu) * rs * gg[j] + bb[j]);
        *(u16x8*)(ln1out + (size_t)row * 512 + lane * 8) = o;
    }
}

// ---------------- V transpose: src [bh][2048][64] -> dst [bh][64][2048] -----
__global__ void transpose_v(const u16* __restrict__ src, u16* __restrict__ dst) {
    __shared__ u16 t[64][66];
    const int bh = blockIdx.x >> 5, kt = blockIdx.x & 31;
    const int tid = threadIdx.x;
    const u16* sp = src + ((size_t)bh * 2048 + kt * 64) * 64;
#pragma unroll
    for (int i = 0; i < 2; ++i) {
        int r = (tid >> 3) + i * 32;
        int c0 = (tid & 7) * 8;
        u16x8 v = *(const u16x8*)(sp + (size_t)r * 64 + c0);
#pragma unroll
        for (int j = 0; j < 8; ++j) t[r][c0 + j] = v[j];
    }
    __syncthreads();
    u16* dp = dst + ((size_t)bh * 64) * 2048 + kt * 64;
#pragma unroll
    for (int i = 0; i < 2; ++i) {
        int d = (tid >> 3) + i * 32;
        int k0 = (tid & 7) * 8;
        u16x8 o;
#pragma unroll
        for (int j = 0; j < 8; ++j) o[j] = t[k0 + j][d];
        *(u16x8*)(dp + (size_t)d * 2048 + k0) = o;
    }
}

// ---------------- LayerNorm over D=512, one wave per row (bf16 in) ----------
__global__ void ln2_kernel(const u16* __restrict__ x, const float* __restrict__ g,
                           const float* __restrict__ b, u16* __restrict__ out) {
    const int w = threadIdx.x >> 6, lane = threadIdx.x & 63;
    const int row = blockIdx.x * 4 + w;
    const u16* xr = x + (size_t)row * 512 + lane * 8;
    u16x8 v = *(const u16x8*)xr;
    float f[8];
#pragma unroll
    for (int j = 0; j < 8; ++j) f[j] = bf2f(v[j]);
    float sum = 0.f, sq = 0.f;
#pragma unroll
    for (int j = 0; j < 8; ++j) { sum += f[j]; sq += f[j] * f[j]; }
#pragma unroll
    for (int m = 1; m < 64; m <<= 1) {
        sum += __shfl_xor(sum, m);
        sq  += __shfl_xor(sq, m);
    }
    float mu = sum * (1.f / 512.f);
    float var = sq * (1.f / 512.f) - mu * mu;
    float rs = rsqrtf(var + 1e-5f);
    float4 g0 = *(const float4*)(g + lane * 8), g1 = *(const float4*)(g + lane * 8 + 4);
    float4 b0 = *(const float4*)(b + lane * 8), b1 = *(const float4*)(b + lane * 8 + 4);
    float gg[8] = {g0.x, g0.y, g0.z, g0.w, g1.x, g1.y, g1.z, g1.w};
    float bb[8] = {b0.x, b0.y, b0.z, b0.w, b1.x, b1.y, b1.z, b1.w};
    u16x8 o;
#pragma unroll
    for (int j = 0; j < 8; ++j) o[j] = f2bf((f[j] - mu) * rs * gg[j] + bb[j]);
    *(u16x8*)(out + (size_t)row * 512 + lane * 8) = o;
}

// ---------------- bf16 MFMA GEMM, C = A[M,K] @ Bt[N,K]^T, fused epilogues ---
// EPI 0: QKV scatter (+bias) -> 3 bf16 [B,H,N,64] outputs (coalesced)
// EPI 1: bf16 out = acc + b0[col] + addf32[row,col]         (stride 512)
// EPI 2: bf16 out = gelu(acc + b0[col])                     (stride 2048)
// EPI 3: f32 out  = acc + b0[col] + bf16(addbf[row,col])    (stride 512)
template <int WM, int WN, int EPI, int MINW>
__global__ __launch_bounds__(256, MINW)
void gemm_bt(const u16* __restrict__ A, const u16* __restrict__ Bt,
             int N, int K,
             const float* __restrict__ b0, const float* __restrict__ b1,
             const float* __restrict__ b2, const float* __restrict__ addf,
             const u16* __restrict__ addbf, float* __restrict__ outf,
             u16* __restrict__ o0, u16* __restrict__ o1, u16* __restrict__ o2) {
    constexpr int BM = 2 * WM, BN = 2 * WN;
    constexpr int MI = WM / 16, NI = WN / 16;
    constexpr int LA = BM / 32, LB = BN / 32;
    __shared__ __align__(16) u16 Als[BM * 64];
    __shared__ __align__(16) u16 Bls[BN * 64];
    const int tid = threadIdx.x, w = tid >> 6, lane = tid & 63;
    // XCD chunk swizzle (all grids %8==0)
    const int bid = ((int)blockIdx.x & 7) * ((int)gridDim.x >> 3) + ((int)blockIdx.x >> 3);
    const int nbn = N / BN;
    const int bm0 = (bid / nbn) * BM;
    const int bn0 = (bid % nbn) * BN;
    const int wr = w >> 1, wc = w & 1;
    const int srow = lane >> 3, schunk = lane & 7;
    f32x4 acc[MI][NI];
#pragma unroll
    for (int i = 0; i < MI; ++i)
#pragma unroll
        for (int j = 0; j < NI; ++j) acc[i][j] = f32x4{0.f, 0.f, 0.f, 0.f};

    for (int k0 = 0; k0 < K; k0 += 64) {
#pragma unroll
        for (int j = 0; j < LA; ++j) {
            int li = w * LA + j;
            int r = li * 8 + srow;
            async16(A + (size_t)(bm0 + r) * K + k0 + ((schunk ^ (r & 7)) << 3), &Als[li * 512]);
        }
#pragma unroll
        for (int j = 0; j < LB; ++j) {
            int li = w * LB + j;
            int r = li * 8 + srow;
            async16(Bt + (size_t)(bn0 + r) * K + k0 + ((schunk ^ (r & 7)) << 3), &Bls[li * 512]);
        }
        __syncthreads();
#pragma unroll
        for (int ks = 0; ks < 2; ++ks) {
            bf16x8 af[MI], bfr[NI];
            const int ck = ks * 4 + (lane >> 4);
#pragma unroll
            for (int mi = 0; mi < MI; ++mi) {
                int r = wr * WM + mi * 16 + (lane & 15);
                af[mi] = *(const bf16x8*)&Als[r * 64 + ((ck ^ (r & 7)) << 3)];
            }
#pragma unroll
            for (int ni = 0; ni < NI; ++ni) {
                int r = wc * WN + ni * 16 + (lane & 15);
                bfr[ni] = *(const bf16x8*)&Bls[r * 64 + ((ck ^ (r & 7)) << 3)];
            }
#pragma unroll
            for (int mi = 0; mi < MI; ++mi)
#pragma unroll
                for (int ni = 0; ni < NI; ++ni)
                    acc[mi][ni] = __builtin_amdgcn_mfma_f32_16x16x32_bf16(
                        af[mi], bfr[ni], acc[mi][ni], 0, 0, 0);
        }
        __syncthreads();
    }
#pragma unroll
    for (int mi = 0; mi < MI; ++mi)
#pragma unroll
        for (int ni = 0; ni < NI; ++ni)
#pragma unroll
            for (int reg = 0; reg < 4; ++reg) {
                int row = bm0 + wr * WM + mi * 16 + ((lane >> 4) << 2) + reg;
                int col = bn0 + wc * WN + ni * 16 + (lane & 15);
                float val = acc[mi][ni][reg];
                if constexpr (EPI == 0) {
                    int wsel = col >> 9, jj = col & 511;
                    const float* bb = wsel == 0 ? b0 : (wsel == 1 ? b1 : b2);
                    u16* dst = wsel == 0 ? o0 : (wsel == 1 ? o1 : o2);
                    val += bb[jj];
                    int h = jj >> 6, hd = jj & 63;
                    int b_ = row >> 11, n_ = row & 2047;
                    dst[(((size_t)(b_ * 8 + h) * 2048 + n_) << 6) + hd] = f2bf(val);
                } else if constexpr (EPI == 1) {
                    val += b0[col] + addf[(size_t)row * 512 + col];
                    o0[(size_t)row * 512 + col] = f2bf(val);
                } else if constexpr (EPI == 2) {
                    float x = val + b0[col];
                    float gx = 0.5f * x * (1.0f + erff(x * 0.70710678118654752f));
                    o0[(size_t)row * 2048 + col] = f2bf(gx);
                } else {
                    val += b0[col] + bf2f(addbf[(size_t)row * 512 + col]);
                    outf[(size_t)row * 512 + col] = val;
                }
            }
}

// ---------------- flash attention, swapped-QK^T, split-K over waves ---------
// R9 configuration (best measured: 92.6us). grid: blockIdx = qt*32 + bh.
// block: 4 waves = (qg in {0,1}) x (ks in {0,1}); wave (qg,ks) does q-rows
// [qt*64+qg*32, +32) against keys [ks*1024, +1024). Fixed-M softmax -> O,L are
// pure sums; cross-ks combine is exact addition via LDS at the end.
// V pre-transposed (vT[bh][hd][key]); staged via global_load_lds (pre-swizzled
// source, linear LDS dest), double-buffered. K direct global->reg (L2-hit).
// __launch_bounds__(256,3): live set ~140 VGPR; the 128-reg cap of minw=4
// spills to scratch (R3/R5/R8/R10: WRITE_SIZE 35-600MB), spill >> occupancy.
__global__ __launch_bounds__(256, 3)
void attn32_kernel(const u16* __restrict__ q, const u16* __restrict__ k,
                   const u16* __restrict__ vT, const u64* __restrict__ adjbits,
                   u16* __restrict__ att) {
    const int tid = threadIdx.x, w = tid >> 6;
    const int lane = tid & 63, col = lane & 31, g = lane >> 5;
    const int qg = w >> 1, ks = w & 1;
    const int bh = blockIdx.x & 31, qt = blockIdx.x >> 5;
    const int b_ = bh >> 3, h_ = bh & 7;
    __shared__ __align__(16) u16 Vt[2][2][4096];   // [ks][buf][64 hd x 64 key], swizzled
    __shared__ float Lls[2][2][32];                // [qg][ks][q]
    const int q0 = qt * 64 + qg * 32;
    const int myq = q0 + col;
    const u16* qptr = q + ((size_t)bh * 2048 + myq) * 64 + g * 8;
    const u16* kptr = k + ((size_t)bh * 2048 + ks * 1024 + col) * 64 + g * 8;
    const u64* adjrow = adjbits + ((size_t)b_ * 2048 + myq) * 32 + ks * 16;
    // staging source: lane covers row r = qg*32 + j*8 + (lane>>3), chunk c = lane&7
    const int sr = lane >> 3, sc = lane & 7;
    const u16* vstage = vT + ((size_t)bh * 64 + qg * 32 + sr) * 2048 + ks * 1024 +
                        ((sc ^ sr) << 3);

    bf16x8 Qf[4];
#pragma unroll
    for (int c = 0; c < 4; ++c) Qf[c] = *(const bf16x8*)(qptr + c * 16);
    f32x16 O0, O1;
#pragma unroll
    for (int i = 0; i < 16; ++i) { O0[i] = 0.f; O1[i] = 0.f; }
    float L = 0.f;

    auto stage = [&](int it, int buf) {
#pragma unroll
        for (int j = 0; j < 4; ++j)
            async16(vstage + (size_t)j * 8 * 2048 + it * 64,
                    &Vt[ks][buf][(qg * 4 + j) * 512]);
    };
    stage(0, 0);
    __syncthreads();

    for (int it = 0; it < 16; ++it) {
        const int cur = it & 1;
        if (it < 15) stage(it + 1, cur ^ 1);
        const u64 adjw = adjrow[it];
        const char* vt = (const char*)&Vt[ks][cur][0];
#pragma unroll
        for (int s = 0; s < 2; ++s) {
            bf16x8 Ku[4];
#pragma unroll
            for (int c = 0; c < 4; ++c)
                Ku[c] = *(const bf16x8*)(kptr + (size_t)(it * 64 + s * 32) * 64 + c * 16);
            f32x16 S;
#pragma unroll
            for (int i = 0; i < 16; ++i) S[i] = 0.f;
            __builtin_amdgcn_s_setprio(1);
#pragma unroll
            for (int c = 0; c < 4; ++c)
                S = __builtin_amdgcn_mfma_f32_32x32x16_bf16(Ku[c], Qf[c], S, 0, 0, 0);
            __builtin_amdgcn_s_setprio(0);
            uint32_t w32 = (uint32_t)(adjw >> (32 * s));
            // P = exp2(S*log2e/8 + cst(edge)); fixed offset M=12 (no online max:
            // masked logits bounded; uniform M cancels exactly in O/L)
            float p[16];
#pragma unroll
            for (int r_ = 0; r_ < 16; ++r_) {
                int bit = (r_ & 3) + 8 * (r_ >> 2) + 4 * g;
                float cst = ((w32 >> bit) & 1u) ? -15.8696454f : -20.7550354f;
                p[r_] = __builtin_amdgcn_exp2f(S[r_] * 0.18033688f + cst);
            }
            float t0 = (p[0] + p[1]) + (p[2] + p[3]);
            float t1 = (p[4] + p[5]) + (p[6] + p[7]);
            float t2s = (p[8] + p[9]) + (p[10] + p[11]);
            float t3 = (p[12] + p[13]) + (p[14] + p[15]);
            L += (t0 + t1) + (t2s + t3);
            // pack to bf16 + permlane redistribution -> PV A-fragments
            uint32_t pk[8];
#pragma unroll
            for (int i = 0; i < 8; ++i) {
                union { __bf16 h[2]; uint32_t u; } pu;
                pu.h[0] = (__bf16)p[2 * i]; pu.h[1] = (__bf16)p[2 * i + 1];
                pk[i] = pu.u;
            }
            permswap(pk[0], pk[2]); permswap(pk[1], pk[3]);
            permswap(pk[4], pk[6]); permswap(pk[5], pk[7]);
            union { uint32_t u[4]; bf16x8 v; } fa0, fa1;
            fa0.u[0] = pk[0]; fa0.u[1] = pk[1]; fa0.u[2] = pk[2]; fa0.u[3] = pk[3];
            fa1.u[0] = pk[4]; fa1.u[1] = pk[5]; fa1.u[2] = pk[6]; fa1.u[3] = pk[7];
            __builtin_amdgcn_s_setprio(1);
#pragma unroll
            for (int c2 = 0; c2 < 2; ++c2) {
                int kb = (s * 32 + c2 * 16 + g * 8) * 2;
                int r0 = col, r1 = 32 + col;
                bf16x8 fv0 = *(const bf16x8*)(vt + ((r0 * 128 + kb) ^ ((r0 & 7) << 4)));
                bf16x8 fv1 = *(const bf16x8*)(vt + ((r1 * 128 + kb) ^ ((r1 & 7) << 4)));
                const bf16x8 fa = c2 ? fa1.v : fa0.v;
                O0 = __builtin_amdgcn_mfma_f32_32x32x16_bf16(fa, fv0, O0, 0, 0, 0);
                O1 = __builtin_amdgcn_mfma_f32_32x32x16_bf16(fa, fv1, O1, 0, 0, 0);
            }
            __builtin_amdgcn_s_setprio(0);
        }
        __syncthreads();
    }

    // cross-g L merge (per q-col), publish per-(qg,ks) L
    float Lt = L + __shfl_xor(L, 32);
    if (g == 0) Lls[qg][ks][col] = Lt;
    __syncthreads();
    // ks=1 publishes O into LDS (reuses Vt space), ks=0 combines + writes out
    float* Obuf = (float*)&Vt[0][0][0];  // [2 qg][32 q][64 hd]
    if (ks == 1) {
#pragma unroll
        for (int r_ = 0; r_ < 16; ++r_) {
            int qrow = (r_ & 3) + 8 * (r_ >> 2) + 4 * g;
            Obuf[((qg * 32 + qrow) << 6) + col] = O0[r_];
            Obuf[((qg * 32 + qrow) << 6) + 32 + col] = O1[r_];
        }
    }
    __syncthreads();
    if (ks == 0) {
        u16* outp = att + ((size_t)b_ * 2048 + q0) * 512 + (h_ << 6);
#pragma unroll
        for (int r_ = 0; r_ < 16; ++r_) {
            int qrow = (r_ & 3) + 8 * (r_ >> 2) + 4 * g;
            float lsum = Lls[qg][0][qrow] + Lls[qg][1][qrow];
            float inv = __builtin_amdgcn_rcpf(lsum);
            float o0 = O0[r_] + Obuf[((qg * 32 + qrow) << 6) + col];
            float o1 = O1[r_] + Obuf[((qg * 32 + qrow) << 6) + 32 + col];
            outp[(size_t)qrow * 512 + col] = f2bf(o0 * inv);
            outp[(size_t)qrow * 512 + 32 + col] = f2bf(o1 * inv);
        }
    }
}

// ---------------------------------------------------------------------------
extern "C" void kernel_launch(void* const* d_in, const int* in_sizes, int n_in,
                              void* d_out, int out_size, void* d_ws, size_t ws_size,
                              hipStream_t stream) {
    const float* hidden = (const float*)d_in[0];
    const float* adj    = (const float*)d_in[1];
    const float* Wq = (const float*)d_in[2];
    const float* bq = (const float*)d_in[3];
    const float* Wk = (const float*)d_in[4];
    const float* bk = (const float*)d_in[5];
    const float* Wv = (const float*)d_in[6];
    const float* bv = (const float*)d_in[7];
    const float* Wo = (const float*)d_in[8];
    const float* bo = (const float*)d_in[9];
    const float* g1 = (const float*)d_in[10];
    const float* b1 = (const float*)d_in[11];
    const float* g2 = (const float*)d_in[12];
    const float* b2 = (const float*)d_in[13];
    const float* Wf1 = (const float*)d_in[14];
    const float* bf1 = (const float*)d_in[15];
    const float* Wf2 = (const float*)d_in[16];
    const float* bf2 = (const float*)d_in[17];
    float* out = (float*)d_out;

    char* p = (char*)d_ws;
    u16* wqkv_t = (u16*)p; p += (size_t)1536 * 512 * 2;
    u16* wo_t   = (u16*)p; p += (size_t)512 * 512 * 2;
    u16* wf1_t  = (u16*)p; p += (size_t)2048 * 512 * 2;
    u16* wf2_t  = (u16*)p; p += (size_t)512 * 2048 * 2;
    u64* adjbits = (u64*)p; p += (size_t)4 * 2048 * 32 * 8;
    u16* bufA = (u16*)p; p += (size_t)8192 * 512 * 2;   // normed, then attended
    u16* bufQ = (u16*)p; p += (size_t)8192 * 512 * 2;   // q, then h2
    float* midreg = (float*)p; p += (size_t)8192 * 512 * 4;  // vT | mid(bf16)
    u16* kbuf = (u16*)p; p += (size_t)8192 * 512 * 2;
    u16* vbuf = (u16*)p; p += (size_t)8192 * 512 * 2;   // V (dead after transpose_v)
    p += (size_t)16 * 1024 * 1024;                       // ffh tail
    u16* ffh = kbuf;  // 8192*2048 bf16 spans kbuf+vbuf+tail (dead after attention)
    u16* vT  = (u16*)midreg;                      // [32 bh][64 hd][2048 key] bf16
    u16* mid = (u16*)midreg + (size_t)8192 * 512; // bf16 mid (disjoint half)
    (void)ws_size; (void)in_sizes; (void)n_in; (void)out_size;

    // prep: weight transposes + adjacency bitmask + LN1 in ONE launch
    prep_kernel<<<4864, 256, 0, stream>>>(Wq, Wk, Wv, Wo, Wf1, Wf2, adj, hidden,
                                          g1, b1, wqkv_t, wo_t, wf1_t, wf2_t,
                                          adjbits, bufA);
    // QKV: Q,K,V all coalesced [B,H,N,64] (+bias)
    gemm_bt<64, 64, 0, 3><<<64 * 12, 256, 0, stream>>>(bufA, wqkv_t, 1536, 512,
        bq, bk, bv, nullptr, nullptr, nullptr, bufQ, kbuf, vbuf);
    transpose_v<<<1024, 256, 0, stream>>>(vbuf, vT);
    attn32_kernel<<<1024, 256, 0, stream>>>(bufQ, kbuf, vT, adjbits, bufA);
    // Wo + bias + residual(hidden f32) -> mid (bf16)
    gemm_bt<32, 64, 1, 4><<<512, 256, 0, stream>>>(bufA, wo_t, 512, 512,
        bo, nullptr, nullptr, hidden, nullptr, nullptr, mid, nullptr, nullptr);
    ln2_kernel<<<2048, 256, 0, stream>>>(mid, g2, b2, bufQ);
    gemm_bt<64, 64, 2, 3><<<64 * 16, 256, 0, stream>>>(bufQ, wf1_t, 2048, 512,
        bf1, nullptr, nullptr, nullptr, nullptr, nullptr, ffh, nullptr, nullptr);
    // FF2 + bias + residual(mid bf16) -> out (f32)
    gemm_bt<32, 64, 3, 4><<<512, 256, 0, stream>>>(ffh, wf2_t, 512, 2048,
        bf2, nullptr, nullptr, nullptr, mid, out, nullptr, nullptr, nullptr);
}